// Round 9
// baseline (213.238 us; speedup 1.0000x reference)
//
#include <hip/hip_runtime.h>

// Problem constants (fixed by the reference):
//   TOTAL_NODES = 262144, NUM_GRAPHS = 1024, MAX_NODES = 512, D = 256
#define NUM_GRAPHS 1024
#define MAX_NODES  512
#define DIM        256
#define D4         (DIM / 4)          // 64 float4 per row (1 KB) = one wave-load

typedef float f4 __attribute__((ext_vector_type(4)));

// lower_bound over the sorted batch_idx (int64 or int32 storage).
__device__ __forceinline__ int lower_bound_idx(const int* __restrict__ b, int n,
                                               bool is64, int key) {
    int lo = 0, hi = n;
    while (lo < hi) {
        int mid = (lo + hi) >> 1;
        int v = is64 ? b[2 * mid] : b[mid];
        if (v < key) lo = mid + 1; else hi = mid;
    }
    return lo;
}

// ---------------------------------------------------------------------------
// R9: deep read/write burst batching + XCD-chunked linear sweep.
//  - Each wave stages 16 rows (16 KB) of emb into registers, THEN issues
//    16 KB of stores: long same-direction bursts to amortize HBM bus
//    turnaround (prior unroll-8 interleaved load/store at 8 KB grain).
//  - blockIdx swizzle: dispatch round-robins blocks across 8 XCDs, so
//    region = (b&7)*256 + (b>>3) gives each XCD one contiguous 64 MB output
//    slab swept linearly — 8 clean fronts instead of 2048 interleaved.
//  - Metadata per block: threads 0/1 binary-search starts[g]/starts[g+1]
//    (proven cheap in R5; block-uniform SGPR values after LDS broadcast).
// ---------------------------------------------------------------------------
__global__ void __launch_bounds__(256)
scatter_states_kernel(const f4* __restrict__ emb,
                      const int* __restrict__ bidx32, int n,
                      f4* __restrict__ out, float* __restrict__ mask) {
    __shared__ int sc[2];
    const int b      = blockIdx.x;                    // 0..2047
    const int region = ((b & 7) << 8) | (b >> 3);     // XCD-chunked remap
    const int g      = region >> 1;                   // graph id
    const int half   = region & 1;                    // 0: slots 0..255, 1: 256..511

    if (threadIdx.x < 2) {
        // int64 detect: little-endian int64 values < 2^31 => int32 view at
        // index n-1 is a hi-word == 0; int32 => max graph id (nonzero here).
        const bool is64 = (bidx32[n - 1] == 0);
        sc[threadIdx.x] = lower_bound_idx(bidx32, n, is64, g + threadIdx.x);
    }
    __syncthreads();
    const int s = sc[0];
    const int c = sc[1] - sc[0];

    const int lane  = threadIdx.x & 63;
    const int w     = threadIdx.x >> 6;       // wave 0..3
    const int rbase = half * 256 + w * 64;    // this wave's first slot (64 rows)

    const f4* wemb = emb + ((size_t)s + rbase) * D4 + lane;
    f4*       wout = out + ((size_t)g * MAX_NODES + rbase) * D4 + lane;

    // 4 tiles x 16 rows. Tiles are fully-copy, fully-zero, or (rarely) mixed.
    for (int t = 0; t < 4; ++t) {
        const int tstart = rbase + t * 16;
        int nc = c - tstart;
        nc = nc < 0 ? 0 : (nc > 16 ? 16 : nc);
        const f4* rs = wemb + (size_t)t * 16 * D4;
        f4*       ws = wout + (size_t)t * 16 * D4;

        if (nc == 16) {                       // pure copy tile: 16 KB burst each way
            f4 buf[16];
#pragma unroll
            for (int i = 0; i < 16; ++i) buf[i] = rs[i * D4];
#pragma unroll
            for (int i = 0; i < 16; ++i) ws[i * D4] = buf[i];
        } else if (nc == 0) {                 // pure zero tile: 16 KB write burst
            const f4 z = (f4)(0.f);
#pragma unroll
            for (int i = 0; i < 16; ++i) ws[i * D4] = z;
        } else {                              // mixed tile: <=1 per graph
            int i = 0;
            for (; i < nc; ++i) ws[i * D4] = rs[i * D4];
            const f4 z = (f4)(0.f);
            for (; i < 16; ++i) ws[i * D4] = z;
        }
    }

    // enc_mask: this block's 256 consecutive mask elements (f32 0/1).
    const int mslot = half * 256 + threadIdx.x;
    mask[(size_t)g * MAX_NODES + mslot] = (mslot < c) ? 1.0f : 0.0f;
}

extern "C" void kernel_launch(void* const* d_in, const int* in_sizes, int n_in,
                              void* d_out, int out_size, void* d_ws, size_t ws_size,
                              hipStream_t stream) {
    const float* node_emb = (const float*)d_in[0];
    const int*   bidx32   = (const int*)d_in[1];   // int32 view; kernel detects int64
    const int    n        = in_sizes[1];           // 262144

    float* mask = (float*)d_out + (size_t)NUM_GRAPHS * MAX_NODES * DIM;
    scatter_states_kernel<<<NUM_GRAPHS * 2, 256, 0, stream>>>(
        (const f4*)node_emb, bidx32, n, (f4*)d_out, mask);
}

// Round 10
// 189.815 us; speedup vs baseline: 1.1234x; 1.1234x over previous
//
#include <hip/hip_runtime.h>

// Problem constants (fixed by the reference):
//   TOTAL_NODES = 262144, NUM_GRAPHS = 1024, MAX_NODES = 512, D = 256
#define NUM_GRAPHS 1024
#define MAX_NODES  512
#define DIM        256
#define D4         (DIM / 4)          // 64 float4 per row (1 KB)
#define TOTAL_V4   (NUM_GRAPHS * MAX_NODES * D4)   // 33,554,432 f4
#define NTHREADS   (2048 * 256)       // 524,288 threads, 64 iters

typedef float f4 __attribute__((ext_vector_type(4)));

// ---------------------------------------------------------------------------
// Kernel 1: boundary scan -> starts[0..1024] (R3's version; ~3 us, coalesced,
// no dependent chains). counts[g] = starts[g+1]-starts[g].
// int64 vs int32 detect: little-endian int64 values < 2^31 => int32 view at
// index n-1 is a hi-word == 0; int32 => max graph id (nonzero here).
// ---------------------------------------------------------------------------
__global__ void scan_offsets_kernel(const int* __restrict__ bidx32, int n,
                                    int* __restrict__ starts) {
    int i = blockIdx.x * blockDim.x + threadIdx.x;
    if (i >= n) return;
    const bool is64 = (bidx32[n - 1] == 0);
    const int cur  = is64 ? bidx32[2 * i] : bidx32[i];
    const int prev = (i == 0) ? -1 : (is64 ? bidx32[2 * (i - 1)] : bidx32[i - 1]);
    for (int g = prev + 1; g <= cur; ++g) starts[g] = i;   // usually 0 iters
    if (i == n - 1) {
        for (int g = cur + 1; g <= NUM_GRAPHS; ++g) starts[g] = n;
    }
}

// ---------------------------------------------------------------------------
// Kernel 2: SINGLE-FRONT grid-stride scatter (the one untested cell:
// single-front + plain cached stores). The whole grid advances as one
// contiguous front through `out` (and, because batch_idx is sorted, through
// `emb` as well) — the same access shape as the 6.29 TB/s copy ubench, vs
// 2048 block-local fronts in the 172 us plateau variants.
// Per-thread invariants (stride 524,288 f4 = 8192 rows = 16 graphs):
//   lane = v&63 and slot = (v>>6)&511 are constant; g = g0 + 16*it.
// Metadata: 2 wave-uniform loads/iter from the L1-resident starts[] table
// (64 lanes same address -> broadcast). Plain loads/stores, unroll 16.
// ---------------------------------------------------------------------------
__global__ void __launch_bounds__(256)
scatter_states_kernel(const f4* __restrict__ emb,
                      const int* __restrict__ starts,
                      f4* __restrict__ out,
                      float* __restrict__ mask) {
    const int tid  = blockIdx.x * blockDim.x + threadIdx.x;   // 0..524287
    const int lane = tid & (D4 - 1);
    const int slot = (tid >> 6) & (MAX_NODES - 1);
    const int g0   = tid >> 15;                               // 0..15

#pragma unroll 16
    for (int it = 0; it < 64; ++it) {
        const int g = g0 + it * 16;
        const int s = starts[g];
        const int c = starts[g + 1] - s;
        f4 val = (f4)(0.f);
        if (slot < c) {
            val = emb[(size_t)(s + slot) * D4 + lane];
        }
        out[(size_t)tid + (size_t)it * NTHREADS] = val;
    }

    // enc_mask: exactly one element per thread (524,288 total), f32 0/1.
    const int mg = tid >> 9;
    const int ms = tid & (MAX_NODES - 1);
    const int mc = starts[mg + 1] - starts[mg];
    mask[tid] = (ms < mc) ? 1.0f : 0.0f;
}

extern "C" void kernel_launch(void* const* d_in, const int* in_sizes, int n_in,
                              void* d_out, int out_size, void* d_ws, size_t ws_size,
                              hipStream_t stream) {
    const float* node_emb = (const float*)d_in[0];
    const int*   bidx32   = (const int*)d_in[1];   // int32 view; kernels detect int64
    const int    n        = in_sizes[1];           // 262144

    int* starts = (int*)d_ws;                      // NUM_GRAPHS + 1 ints

    scan_offsets_kernel<<<(n + 255) / 256, 256, 0, stream>>>(bidx32, n, starts);

    float* mask = (float*)d_out + (size_t)NUM_GRAPHS * MAX_NODES * DIM;
    scatter_states_kernel<<<NTHREADS / 256, 256, 0, stream>>>(
        (const f4*)node_emb, starts, (f4*)d_out, mask);
}

// Round 11
// 181.409 us; speedup vs baseline: 1.1755x; 1.0463x over previous
//
#include <hip/hip_runtime.h>

// Problem constants (fixed by the reference):
//   TOTAL_NODES = 262144, NUM_GRAPHS = 1024, MAX_NODES = 512, D = 256
#define NUM_GRAPHS 1024
#define MAX_NODES  512
#define DIM        256
#define D4         (DIM / 4)          // 64 float4 per row (1 KB) = one wave-load

typedef float f4 __attribute__((ext_vector_type(4)));

// ---------------------------------------------------------------------------
// R11: terminal polish of the best variant (R5, 172.3 us).
//  - 4096 blocks (16384 waves, 32 rows per wave): continues the measured
//    monotone trend (512 rows/wave: 179 -> 128: 173.5 -> 64: 172.3).
//  - Wave-lockstep metadata search (all lanes run lower_bound(g + (lane&1)),
//    __shfl broadcast): removes the LDS round-trip + __syncthreads of R5.
//  - Mask stores issued BEFORE the bulk loop (independent work up front).
//  - Plain cached loads/stores, interleaved copy loop (compiler-pipelined) —
//    the proven-best micro-shape (nt and register-staging both regressed).
// ---------------------------------------------------------------------------
__global__ void __launch_bounds__(256)
scatter_states_kernel(const f4* __restrict__ emb,
                      const int* __restrict__ bidx32, int n,
                      f4* __restrict__ out, float* __restrict__ mask) {
    const int b    = blockIdx.x;            // 0..4095
    const int g    = b >> 2;                // graph id
    const int q    = b & 3;                 // quarter of the graph's 512 rows
    const int lane = threadIdx.x & 63;
    const int w    = threadIdx.x >> 6;      // wave 0..3

    // int64 detect: little-endian int64 values < 2^31 => int32 view at index
    // n-1 is a hi-word == 0; int32 => it's the max graph id (nonzero here).
    const bool is64 = (bidx32[n - 1] == 0);

    // Wave-lockstep binary search, no divergence: lane k (k&1) seeks g+k.
    const int key = g + (lane & 1);
    int lo = 0, hi = n;
    while (lo < hi) {
        int mid = (lo + hi) >> 1;
        int v = is64 ? bidx32[2 * mid] : bidx32[mid];
        if (v < key) lo = mid + 1; else hi = mid;
    }
    const int s = __shfl(lo, 0, 64);
    const int c = __shfl(lo, 1, 64) - s;    // rows of graph g

    // enc_mask early (independent of the bulk stream): q==0 blocks only.
    if (q == 0) {
        float* mg = mask + (size_t)g * MAX_NODES;
        mg[threadIdx.x]       = ((int)threadIdx.x < c)       ? 1.0f : 0.0f;
        mg[256 + threadIdx.x] = (256 + (int)threadIdx.x < c) ? 1.0f : 0.0f;
    }

    // This wave's contiguous 32-row (32 KB) range.
    const int rbase = q * 128 + w * 32;
    const f4* wemb = emb + ((size_t)s + rbase) * D4 + lane;
    f4*       wout = out + ((size_t)g * MAX_NODES + rbase) * D4 + lane;

    int ncopy = c - rbase;                  // occupied rows in this range
    ncopy = ncopy < 0 ? 0 : (ncopy > 32 ? 32 : ncopy);

    int it = 0;
#pragma unroll 16
    for (; it < ncopy; ++it)                // copy phase
        wout[it * D4] = wemb[it * D4];
    const f4 z = (f4)(0.f);
#pragma unroll 16
    for (; it < 32; ++it)                   // zero-fill phase
        wout[it * D4] = z;
}

extern "C" void kernel_launch(void* const* d_in, const int* in_sizes, int n_in,
                              void* d_out, int out_size, void* d_ws, size_t ws_size,
                              hipStream_t stream) {
    const float* node_emb = (const float*)d_in[0];
    const int*   bidx32   = (const int*)d_in[1];   // int32 view; kernel detects int64
    const int    n        = in_sizes[1];           // 262144

    float* mask = (float*)d_out + (size_t)NUM_GRAPHS * MAX_NODES * DIM;
    scatter_states_kernel<<<NUM_GRAPHS * 4, 256, 0, stream>>>(
        (const f4*)node_emb, bidx32, n, (f4*)d_out, mask);
}

// Round 12
// 173.458 us; speedup vs baseline: 1.2293x; 1.0458x over previous
//
#include <hip/hip_runtime.h>

// Problem constants (fixed by the reference):
//   TOTAL_NODES = 262144, NUM_GRAPHS = 1024, MAX_NODES = 512, D = 256
#define NUM_GRAPHS 1024
#define MAX_NODES  512
#define DIM        256
#define D4         (DIM / 4)          // 64 float4 per row (1 KB)

typedef float f4 __attribute__((ext_vector_type(4)));

// lower_bound over the sorted batch_idx (int64 or int32 storage).
__device__ __forceinline__ int lower_bound_idx(const int* __restrict__ b, int n,
                                               bool is64, int key) {
    int lo = 0, hi = n;
    while (lo < hi) {
        int mid = (lo + hi) >> 1;
        int v = is64 ? b[2 * mid] : b[mid];
        if (v < key) lo = mid + 1; else hi = mid;
    }
    return lo;
}

// ---------------------------------------------------------------------------
// PROVEN-BEST configuration (R5, 172.3 us; R11's "polish" regressed to 181).
// Single fused kernel, 2 blocks per graph. Block b owns graph g = b>>1,
// slot range [256*(b&1), +256) — a contiguous 256 KB output span. Threads
// 0/1 binary-search starts[g] / starts[g+1] (bidx L2-resident; ~18 dependent
// loads, parallel across 2048 blocks), LDS-broadcast to the block.
// Each wave streams a contiguous 64-row (64 KB) range: interleaved
// compiler-pipelined copy loop for occupied rows, then zero-fill loop.
// Plain cached loads/stores (nt hints and register burst-staging both
// measured slower). Exhaustive structure search (R2-R11) shows every mixed
// R/W variant lands 172-213 us at identical 807 MB traffic — this is the
// empirical mixed-stream ceiling on this part.
// ---------------------------------------------------------------------------
__global__ void __launch_bounds__(256)
scatter_states_kernel(const f4* __restrict__ emb,
                      const int* __restrict__ bidx32, int n,
                      f4* __restrict__ out, float* __restrict__ mask) {
    __shared__ int sc[2];
    const int b    = blockIdx.x;        // 0..2047
    const int g    = b >> 1;            // graph id
    const int half = b & 1;             // 0: slots 0..255, 1: 256..511

    if (threadIdx.x < 2) {
        // int64 detect: little-endian int64 values < 2^31 => int32 view at
        // index n-1 is a hi-word == 0; int32 => it's the max graph id (!=0).
        const bool is64 = (bidx32[n - 1] == 0);
        sc[threadIdx.x] = lower_bound_idx(bidx32, n, is64, g + threadIdx.x);
    }
    __syncthreads();
    const int s = sc[0];
    const int c = sc[1] - sc[0];

    const int lane  = threadIdx.x & 63;
    const int w     = threadIdx.x >> 6;       // wave 0..3
    const int rbase = half * 256 + w * 64;    // this wave's first slot

    // Per-wave contiguous streams: 64 rows x 1 KB.
    const f4* wemb = emb + (size_t)(s + rbase) * D4 + lane;
    f4*       wout = out + ((size_t)g * MAX_NODES + rbase) * D4 + lane;

    int ncopy = c - rbase;                    // occupied rows in this range
    ncopy = ncopy < 0 ? 0 : (ncopy > 64 ? 64 : ncopy);

    int it = 0;
#pragma unroll 8
    for (; it < ncopy; ++it)
        wout[it * D4] = wemb[it * D4];
    const f4 z = (f4)(0.f);
#pragma unroll 8
    for (; it < 64; ++it)
        wout[it * D4] = z;

    // enc_mask: this block's 256 consecutive mask elements (f32 0/1).
    const int mslot = half * 256 + threadIdx.x;
    mask[(size_t)g * MAX_NODES + mslot] = (mslot < c) ? 1.0f : 0.0f;
}

extern "C" void kernel_launch(void* const* d_in, const int* in_sizes, int n_in,
                              void* d_out, int out_size, void* d_ws, size_t ws_size,
                              hipStream_t stream) {
    const float* node_emb = (const float*)d_in[0];
    const int*   bidx32   = (const int*)d_in[1];   // int32 view; kernel detects int64
    const int    n        = in_sizes[1];           // 262144

    float* mask = (float*)d_out + (size_t)NUM_GRAPHS * MAX_NODES * DIM;
    scatter_states_kernel<<<NUM_GRAPHS * 2, 256, 0, stream>>>(
        (const f4*)node_emb, bidx32, n, (f4*)d_out, mask);
}